// Round 2
// baseline (1897.560 us; speedup 1.0000x reference)
//
#include <hip/hip_runtime.h>
#include <hip/hip_bf16.h>

#define NCH 128      // n_agt == n_ctx
#define TB  16       // edges (or nodes) per block

static_assert(NCH == 128, "channel count fixed at 128");

// ---------------------------------------------------------------------------
// Block-wide (128 threads = 2 waves) GroupNorm over the channel dim for TB
// rows at once. acc[i] holds this thread's channel value for row i.
// Writes (optionally ReLU'd) normalized value to dst[i][t].
// ---------------------------------------------------------------------------
template<bool RELU>
__device__ inline void gn_write(float (&acc)[TB],
                                const float* __restrict__ gamma,
                                const float* __restrict__ beta,
                                float (*dst)[NCH],
                                float (*red_s)[2], float (*red_q)[2],
                                int t)
{
    __syncthreads();   // prior readers of red_* / dst done
#pragma unroll
    for (int i = 0; i < TB; ++i) {
        float s = acc[i];
        float q = acc[i] * acc[i];
        for (int off = 32; off > 0; off >>= 1) {
            s += __shfl_down(s, off);
            q += __shfl_down(q, off);
        }
        if ((t & 63) == 0) { red_s[i][t >> 6] = s; red_q[i][t >> 6] = q; }
    }
    __syncthreads();
    const float g = gamma[t];
    const float b = beta[t];
#pragma unroll
    for (int i = 0; i < TB; ++i) {
        float s  = red_s[i][0] + red_s[i][1];
        float q  = red_q[i][0] + red_q[i][1];
        float mu = s * (1.f / NCH);
        float var = q * (1.f / NCH) - mu * mu;
        float rs = rsqrtf(var + 1e-5f);
        float v = (acc[i] - mu) * rs * g + b;
        if (RELU) v = fmaxf(v, 0.f);
        dst[i][t] = v;
    }
    __syncthreads();
}

// ---------------------------------------------------------------------------
// out = agts @ w_a^T   (per node 128x128 matvec), batched TB nodes per block
// ---------------------------------------------------------------------------
__global__ __launch_bounds__(128) void node_init_kernel(
    const float* __restrict__ agts, const float* __restrict__ w_a,
    float* __restrict__ outbuf, int N)
{
    const int t  = threadIdx.x;
    const int n0 = blockIdx.x * TB;
    __shared__ float sh[TB][NCH];
#pragma unroll
    for (int i = 0; i < TB; ++i) {
        int n = n0 + i; if (n >= N) n = N - 1;
        sh[i][t] = agts[(size_t)n * NCH + t];
    }
    __syncthreads();
    float acc[TB];
#pragma unroll
    for (int i = 0; i < TB; ++i) acc[i] = 0.f;
    const float4* wr = (const float4*)(w_a + (size_t)t * NCH);
    for (int k4 = 0; k4 < NCH / 4; ++k4) {
        float4 wv = wr[k4];
#pragma unroll
        for (int i = 0; i < TB; ++i) {
            float4 xv = *(const float4*)&sh[i][k4 * 4];
            acc[i] = fmaf(wv.x, xv.x, acc[i]);
            acc[i] = fmaf(wv.y, xv.y, acc[i]);
            acc[i] = fmaf(wv.z, xv.z, acc[i]);
            acc[i] = fmaf(wv.w, xv.w, acc[i]);
        }
    }
#pragma unroll
    for (int i = 0; i < TB; ++i) {
        int n = n0 + i;
        if (n < N) outbuf[(size_t)n * NCH + t] = acc[i];
    }
}

// ---------------------------------------------------------------------------
// Fused edge pipeline: dist MLP -> query -> concat/ctx MLP -> scatter-add
// TB edges per 128-thread block; all activations live in LDS.
// ---------------------------------------------------------------------------
__global__ __launch_bounds__(128) void edge_kernel(
    const float* __restrict__ agts, const float* __restrict__ ctx,
    const float* __restrict__ agt_ctrs, const float* __restrict__ ctx_ctrs,
    const int* __restrict__ hi, const int* __restrict__ wi,
    const float* __restrict__ w_d1, const float* __restrict__ b_d1,
    const float* __restrict__ w_d2, const float* __restrict__ g_d2, const float* __restrict__ bt_d2,
    const float* __restrict__ w_q, const float* __restrict__ g_q, const float* __restrict__ bt_q,
    const float* __restrict__ w_c1, const float* __restrict__ g_c1, const float* __restrict__ bt_c1,
    const float* __restrict__ w_c2,
    float* __restrict__ outbuf, int E)
{
    const int t  = threadIdx.x;
    const int e0 = blockIdx.x * TB;
    __shared__ float sh_a[TB][NCH];   // agts rows; reused as c1 output
    __shared__ float sh_x[TB][NCH];   // ctx rows
    __shared__ float sh_d[TB][NCH];   // dist features
    __shared__ float sh_q[TB][NCH];   // query features
    __shared__ float red_s[TB][2], red_q2[TB][2];

    int   hn[TB];
    float dx[TB], dy[TB];
#pragma unroll
    for (int i = 0; i < TB; ++i) {
        int e = e0 + i; if (e >= E) e = E - 1;
        const int h = hi[e];
        const int w = wi[e];
        hn[i] = h;
        sh_a[i][t] = agts[(size_t)h * NCH + t];
        sh_x[i][t] = ctx[(size_t)w * NCH + t];
        dx[i] = agt_ctrs[2 * h]     - ctx_ctrs[2 * w];
        dy[i] = agt_ctrs[2 * h + 1] - ctx_ctrs[2 * w + 1];
    }
    // ---- dist layer 1: relu(W1 @ [dx,dy] + b1) ----
    {
        const float w0 = w_d1[2 * t], w1 = w_d1[2 * t + 1], b0 = b_d1[t];
#pragma unroll
        for (int i = 0; i < TB; ++i)
            sh_d[i][t] = fmaxf(fmaf(w0, dx[i], fmaf(w1, dy[i], b0)), 0.f);
    }
    __syncthreads();

    float acc[TB];
    // ---- dist layer 2: relu(GN(W2 @ d)) ----
    {
#pragma unroll
        for (int i = 0; i < TB; ++i) acc[i] = 0.f;
        const float4* wr = (const float4*)(w_d2 + (size_t)t * NCH);
        for (int k4 = 0; k4 < NCH / 4; ++k4) {
            float4 wv = wr[k4];
#pragma unroll
            for (int i = 0; i < TB; ++i) {
                float4 xv = *(const float4*)&sh_d[i][k4 * 4];
                acc[i] = fmaf(wv.x, xv.x, acc[i]);
                acc[i] = fmaf(wv.y, xv.y, acc[i]);
                acc[i] = fmaf(wv.z, xv.z, acc[i]);
                acc[i] = fmaf(wv.w, xv.w, acc[i]);
            }
        }
        gn_write<true>(acc, g_d2, bt_d2, sh_d, red_s, red_q2, t);
    }
    // ---- query: relu(GN(Wq @ agts[hi])) ----
    {
#pragma unroll
        for (int i = 0; i < TB; ++i) acc[i] = 0.f;
        const float4* wr = (const float4*)(w_q + (size_t)t * NCH);
        for (int k4 = 0; k4 < NCH / 4; ++k4) {
            float4 wv = wr[k4];
#pragma unroll
            for (int i = 0; i < TB; ++i) {
                float4 xv = *(const float4*)&sh_a[i][k4 * 4];
                acc[i] = fmaf(wv.x, xv.x, acc[i]);
                acc[i] = fmaf(wv.y, xv.y, acc[i]);
                acc[i] = fmaf(wv.z, xv.z, acc[i]);
                acc[i] = fmaf(wv.w, xv.w, acc[i]);
            }
        }
        gn_write<true>(acc, g_q, bt_q, sh_q, red_s, red_q2, t);
    }
    // ---- ctx fuse: relu(GN(Wc1 @ [d, q, ctx])) ----  (output into sh_a)
    {
#pragma unroll
        for (int i = 0; i < TB; ++i) acc[i] = 0.f;
        const float4* wr = (const float4*)(w_c1 + (size_t)t * 3 * NCH);
        for (int k4 = 0; k4 < NCH / 4; ++k4) {
            float4 wv = wr[k4];
#pragma unroll
            for (int i = 0; i < TB; ++i) {
                float4 xv = *(const float4*)&sh_d[i][k4 * 4];
                acc[i] = fmaf(wv.x, xv.x, acc[i]);
                acc[i] = fmaf(wv.y, xv.y, acc[i]);
                acc[i] = fmaf(wv.z, xv.z, acc[i]);
                acc[i] = fmaf(wv.w, xv.w, acc[i]);
            }
        }
        for (int k4 = 0; k4 < NCH / 4; ++k4) {
            float4 wv = wr[NCH / 4 + k4];
#pragma unroll
            for (int i = 0; i < TB; ++i) {
                float4 xv = *(const float4*)&sh_q[i][k4 * 4];
                acc[i] = fmaf(wv.x, xv.x, acc[i]);
                acc[i] = fmaf(wv.y, xv.y, acc[i]);
                acc[i] = fmaf(wv.z, xv.z, acc[i]);
                acc[i] = fmaf(wv.w, xv.w, acc[i]);
            }
        }
        for (int k4 = 0; k4 < NCH / 4; ++k4) {
            float4 wv = wr[2 * (NCH / 4) + k4];
#pragma unroll
            for (int i = 0; i < TB; ++i) {
                float4 xv = *(const float4*)&sh_x[i][k4 * 4];
                acc[i] = fmaf(wv.x, xv.x, acc[i]);
                acc[i] = fmaf(wv.y, xv.y, acc[i]);
                acc[i] = fmaf(wv.z, xv.z, acc[i]);
                acc[i] = fmaf(wv.w, xv.w, acc[i]);
            }
        }
        gn_write<true>(acc, g_c1, bt_c1, sh_a, red_s, red_q2, t);
    }
    // ---- final linear Wc2 + scatter-add ----
    {
#pragma unroll
        for (int i = 0; i < TB; ++i) acc[i] = 0.f;
        const float4* wr = (const float4*)(w_c2 + (size_t)t * NCH);
        for (int k4 = 0; k4 < NCH / 4; ++k4) {
            float4 wv = wr[k4];
#pragma unroll
            for (int i = 0; i < TB; ++i) {
                float4 xv = *(const float4*)&sh_a[i][k4 * 4];
                acc[i] = fmaf(wv.x, xv.x, acc[i]);
                acc[i] = fmaf(wv.y, xv.y, acc[i]);
                acc[i] = fmaf(wv.z, xv.z, acc[i]);
                acc[i] = fmaf(wv.w, xv.w, acc[i]);
            }
        }
#pragma unroll
        for (int i = 0; i < TB; ++i) {
            if (e0 + i < E)
                atomicAdd(&outbuf[(size_t)hn[i] * NCH + t], acc[i]);
        }
    }
}

// ---------------------------------------------------------------------------
// Node post: relu(GN(out)) -> GN(out @ w_l^T) -> relu(+ res) -> f32
// In-place on outbuf (== d_out): each row is owned by exactly one block.
// ---------------------------------------------------------------------------
__global__ __launch_bounds__(128) void node_post_kernel(
    float* __restrict__ outbuf, const float* __restrict__ agts,
    const float* __restrict__ g_n, const float* __restrict__ bt_n,
    const float* __restrict__ w_l, const float* __restrict__ g_l, const float* __restrict__ bt_l,
    int N)
{
    const int t  = threadIdx.x;
    const int n0 = blockIdx.x * TB;
    __shared__ float sh[TB][NCH];
    __shared__ float red_s[TB][2], red_q2[TB][2];

    float acc[TB];
#pragma unroll
    for (int i = 0; i < TB; ++i) {
        int n = n0 + i; if (n >= N) n = N - 1;
        acc[i] = outbuf[(size_t)n * NCH + t];
    }
    gn_write<true>(acc, g_n, bt_n, sh, red_s, red_q2, t);

    // linear: acc = W_l @ sh
#pragma unroll
    for (int i = 0; i < TB; ++i) acc[i] = 0.f;
    const float4* wr = (const float4*)(w_l + (size_t)t * NCH);
    for (int k4 = 0; k4 < NCH / 4; ++k4) {
        float4 wv = wr[k4];
#pragma unroll
        for (int i = 0; i < TB; ++i) {
            float4 xv = *(const float4*)&sh[i][k4 * 4];
            acc[i] = fmaf(wv.x, xv.x, acc[i]);
            acc[i] = fmaf(wv.y, xv.y, acc[i]);
            acc[i] = fmaf(wv.z, xv.z, acc[i]);
            acc[i] = fmaf(wv.w, xv.w, acc[i]);
        }
    }
    // GN (no relu), + residual, relu, f32 store (in place)
    __syncthreads();
#pragma unroll
    for (int i = 0; i < TB; ++i) {
        float s = acc[i];
        float q = acc[i] * acc[i];
        for (int off = 32; off > 0; off >>= 1) {
            s += __shfl_down(s, off);
            q += __shfl_down(q, off);
        }
        if ((t & 63) == 0) { red_s[i][t >> 6] = s; red_q2[i][t >> 6] = q; }
    }
    __syncthreads();
    const float g = g_l[t];
    const float b = bt_l[t];
#pragma unroll
    for (int i = 0; i < TB; ++i) {
        float s  = red_s[i][0] + red_s[i][1];
        float q  = red_q2[i][0] + red_q2[i][1];
        float mu = s * (1.f / NCH);
        float var = q * (1.f / NCH) - mu * mu;
        float rs = rsqrtf(var + 1e-5f);
        float v  = (acc[i] - mu) * rs * g + b;
        int n = n0 + i;
        if (n < N) {
            float r = agts[(size_t)n * NCH + t];
            outbuf[(size_t)n * NCH + t] = fmaxf(v + r, 0.f);
        }
    }
}

// ---------------------------------------------------------------------------
extern "C" void kernel_launch(void* const* d_in, const int* in_sizes, int n_in,
                              void* d_out, int out_size, void* d_ws, size_t ws_size,
                              hipStream_t stream) {
    const float* agts     = (const float*)d_in[0];
    const float* ctx      = (const float*)d_in[1];
    const float* agt_ctrs = (const float*)d_in[2];
    const float* ctx_ctrs = (const float*)d_in[3];
    const int*   hi       = (const int*)d_in[4];
    const int*   wi       = (const int*)d_in[5];
    const float* w_d1     = (const float*)d_in[6];
    const float* b_d1     = (const float*)d_in[7];
    const float* w_d2     = (const float*)d_in[8];
    const float* g_d2     = (const float*)d_in[9];
    const float* bt_d2    = (const float*)d_in[10];
    const float* w_q      = (const float*)d_in[11];
    const float* g_q      = (const float*)d_in[12];
    const float* bt_q     = (const float*)d_in[13];
    const float* w_c1     = (const float*)d_in[14];
    const float* g_c1     = (const float*)d_in[15];
    const float* bt_c1    = (const float*)d_in[16];
    const float* w_c2     = (const float*)d_in[17];
    const float* w_a      = (const float*)d_in[18];
    const float* g_n      = (const float*)d_in[19];
    const float* bt_n     = (const float*)d_in[20];
    const float* w_l      = (const float*)d_in[21];
    const float* g_l      = (const float*)d_in[22];
    const float* bt_l     = (const float*)d_in[23];

    const int N = in_sizes[0] / NCH;
    const int E = in_sizes[4];

    // d_out is an [N,128] float32 buffer — use it directly as the f32
    // accumulator (node_init fully writes it; edges atomicAdd; node_post
    // rewrites it in place). No workspace needed.
    float* outbuf = (float*)d_out;

    const int nb_nodes = (N + TB - 1) / TB;
    const int nb_edges = (E + TB - 1) / TB;

    node_init_kernel<<<nb_nodes, 128, 0, stream>>>(agts, w_a, outbuf, N);
    edge_kernel<<<nb_edges, 128, 0, stream>>>(
        agts, ctx, agt_ctrs, ctx_ctrs, hi, wi,
        w_d1, b_d1, w_d2, g_d2, bt_d2,
        w_q, g_q, bt_q,
        w_c1, g_c1, bt_c1, w_c2,
        outbuf, E);
    node_post_kernel<<<nb_nodes, 128, 0, stream>>>(
        outbuf, agts, g_n, bt_n, w_l, g_l, bt_l, N);
}

// Round 3
// 578.711 us; speedup vs baseline: 3.2789x; 3.2789x over previous
//
#include <hip/hip_runtime.h>
#include <hip/hip_bf16.h>

#define NCH 128      // n_agt == n_ctx
#define EB  32       // edges per block (edge kernel)
#define TB  16       // nodes per block (node kernels)

typedef __attribute__((ext_vector_type(8))) short bf16x8;
typedef __attribute__((ext_vector_type(4))) float f32x4;

__device__ inline unsigned short f2bf(float v) {
    __hip_bfloat16 h = __float2bfloat16(v);
    return __builtin_bit_cast(unsigned short, h);
}

// ---------------------------------------------------------------------------
// Convert the four edge-GEMM weight matrices to bf16 in d_ws.
// Layout: Wd2[128x128] | Wq[128x128] | Wc1[128x384] | Wc2[128x128]
// ---------------------------------------------------------------------------
__global__ __launch_bounds__(256) void convert_weights_kernel(
    const float* __restrict__ w_d2, const float* __restrict__ w_q,
    const float* __restrict__ w_c1, const float* __restrict__ w_c2,
    unsigned short* __restrict__ out)
{
    int i = blockIdx.x * 256 + threadIdx.x;
    const float* src; int off;
    if      (i < 16384) { src = w_d2; off = i; }
    else if (i < 32768) { src = w_q;  off = i - 16384; }
    else if (i < 81920) { src = w_c1; off = i - 32768; }
    else if (i < 98304) { src = w_c2; off = i - 81920; }
    else return;
    out[i] = f2bf(src[off]);
}

// ---------------------------------------------------------------------------
// One K=128 GEMM step on 32 edges: acc[m][n] += A(32x128,bf16,swizzled LDS)
//   x W^T (W row-major [128 out][128 k] bf16, from global/L2).
// Wave covers out-channels [wave*32, wave*32+32), all 32 edge rows.
// ---------------------------------------------------------------------------
__device__ inline void gemm_k128(const unsigned short* A, const unsigned short* W,
                                 int lane, int wave, f32x4 (&acc)[2][2])
{
#pragma unroll
    for (int k = 0; k < 4; ++k) {
        const int koff = k * 32 + (lane >> 4) * 8;
        bf16x8 a[2], b[2];
#pragma unroll
        for (int m = 0; m < 2; ++m) {
            int r = m * 16 + (lane & 15);
            int byte = (r * 256 + koff * 2) ^ ((r & 7) << 4);
            a[m] = *(const bf16x8*)((const char*)A + byte);
        }
#pragma unroll
        for (int n = 0; n < 2; ++n) {
            int wr = wave * 32 + n * 16 + (lane & 15);
            b[n] = *(const bf16x8*)(W + (size_t)wr * NCH + koff);
        }
#pragma unroll
        for (int m = 0; m < 2; ++m)
#pragma unroll
            for (int n = 0; n < 2; ++n)
                acc[m][n] = __builtin_amdgcn_mfma_f32_16x16x32_bf16(a[m], b[n], acc[m][n], 0, 0, 0);
    }
}

// ---------------------------------------------------------------------------
// GroupNorm(1) over 128 channels for 32 rows, from MFMA fragments, with ReLU,
// writing bf16 (pair-packed) into swizzled LDS dst.
// ---------------------------------------------------------------------------
__device__ inline void gn_store(f32x4 (&acc)[2][2],
                                const float* __restrict__ gamma,
                                const float* __restrict__ beta,
                                float (*stg)[NCH + 4],
                                float (*red_s)[2], float (*red_q)[2],
                                unsigned short* dst, int t)
{
    const int lane = t & 63, wave = t >> 6;
    // frags -> padded f32 staging (conflict-free: 132-stride)
#pragma unroll
    for (int m = 0; m < 2; ++m)
#pragma unroll
        for (int n = 0; n < 2; ++n)
#pragma unroll
            for (int j = 0; j < 4; ++j)
                stg[m * 16 + ((lane >> 4) << 2) + j][wave * 32 + n * 16 + (lane & 15)] = acc[m][n][j];
    __syncthreads();

    const int c = t & 127, rh = t >> 7;
    const float g = gamma[c], b = beta[c];
    float v[16];
#pragma unroll
    for (int i = 0; i < 16; ++i) {
        int r = rh * 16 + i;
        float x = stg[r][c];
        v[i] = x;
        float s = x, q = x * x;
        for (int off = 32; off > 0; off >>= 1) {
            s += __shfl_down(s, off);
            q += __shfl_down(q, off);
        }
        if (lane == 0) { red_s[r][wave & 1] = s; red_q[r][wave & 1] = q; }
    }
    __syncthreads();
#pragma unroll
    for (int i = 0; i < 16; ++i) {
        int r = rh * 16 + i;
        float s = red_s[r][0] + red_s[r][1];
        float q = red_q[r][0] + red_q[r][1];
        float mu  = s * (1.f / NCH);
        float var = q * (1.f / NCH) - mu * mu;
        float rs  = rsqrtf(var + 1e-5f);
        float o = fmaxf((v[i] - mu) * rs * g + b, 0.f);
        unsigned int pv = f2bf(o);
        unsigned int ov = __shfl_xor(pv, 1);
        if (!(c & 1)) {
            int byte = (r * 256 + c * 2) ^ ((r & 7) << 4);
            *(unsigned int*)((char*)dst + byte) = (pv & 0xffffu) | (ov << 16);
        }
    }
    __syncthreads();
}

// ---------------------------------------------------------------------------
// Fused edge pipeline (MFMA): d1 -> d2(GN) ; q(GN) ; c1(GN, K=384) ; c2 -> scatter
// ---------------------------------------------------------------------------
__global__ __launch_bounds__(256) void edge_kernel(
    const float* __restrict__ agts, const float* __restrict__ ctx,
    const float* __restrict__ agt_ctrs, const float* __restrict__ ctx_ctrs,
    const int* __restrict__ hi, const int* __restrict__ wi,
    const float* __restrict__ w_d1, const float* __restrict__ b_d1,
    const float* __restrict__ g_d2, const float* __restrict__ bt_d2,
    const float* __restrict__ g_q, const float* __restrict__ bt_q,
    const float* __restrict__ g_c1, const float* __restrict__ bt_c1,
    const unsigned short* __restrict__ wbf,
    float* __restrict__ outbuf, int E)
{
    const int t = threadIdx.x;
    const int lane = t & 63;
    const int wave = t >> 6;
    const int e0 = blockIdx.x * EB;

    __shared__ unsigned short bfA[EB * NCH];   // agts[hi] bf16; later c1
    __shared__ unsigned short bfD[EB * NCH];   // d1; later d2
    __shared__ unsigned short bfQ[EB * NCH];   // q
    __shared__ unsigned short bfX[EB * NCH];   // ctx[wi]
    __shared__ float stg[EB][NCH + 4];
    __shared__ float red_s[EB][2], red_q[EB][2];
    __shared__ int   sh_h[EB], sh_w[EB];
    __shared__ float sh_dx[EB], sh_dy[EB];

    const unsigned short* Wd2 = wbf;
    const unsigned short* Wq  = wbf + 16384;
    const unsigned short* Wc1 = wbf + 32768;
    const unsigned short* Wc2 = wbf + 81920;

    if (t < EB) {
        int e = e0 + t; if (e >= E) e = E - 1;
        int h = hi[e], w = wi[e];
        sh_h[t] = h; sh_w[t] = w;
        sh_dx[t] = agt_ctrs[2 * h]     - ctx_ctrs[2 * w];
        sh_dy[t] = agt_ctrs[2 * h + 1] - ctx_ctrs[2 * w + 1];
    }
    __syncthreads();

    // gather agts[hi], ctx[wi] -> bf16 swizzled LDS (float4 loads, 8B LDS stores)
    {
        const int c4 = (t & 31) * 4;
        const int rr = t >> 5;
#pragma unroll
        for (int p = 0; p < 4; ++p) {
            int r = p * 8 + rr;
            float4 av = *(const float4*)&agts[(size_t)sh_h[r] * NCH + c4];
            float4 xv = *(const float4*)&ctx [(size_t)sh_w[r] * NCH + c4];
            int byte = (r * 256 + c4 * 2) ^ ((r & 7) << 4);
            ushort4 ao = { f2bf(av.x), f2bf(av.y), f2bf(av.z), f2bf(av.w) };
            ushort4 xo = { f2bf(xv.x), f2bf(xv.y), f2bf(xv.z), f2bf(xv.w) };
            *(ushort4*)((char*)bfA + byte) = ao;
            *(ushort4*)((char*)bfX + byte) = xo;
        }
    }
    // d1 = relu(w_d1 . [dx,dy] + b_d1)   -> bfD
    {
        const int c = t & 127, rh = t >> 7;
        const float w0 = w_d1[2 * c], w1 = w_d1[2 * c + 1], b0 = b_d1[c];
#pragma unroll
        for (int i = 0; i < 16; ++i) {
            int r = rh * 16 + i;
            float v = fmaxf(fmaf(w0, sh_dx[r], fmaf(w1, sh_dy[r], b0)), 0.f);
            unsigned int pv = f2bf(v);
            unsigned int ov = __shfl_xor(pv, 1);
            if (!(c & 1)) {
                int byte = (r * 256 + c * 2) ^ ((r & 7) << 4);
                *(unsigned int*)((char*)bfD + byte) = (pv & 0xffffu) | (ov << 16);
            }
        }
    }
    __syncthreads();

    const f32x4 z = { 0.f, 0.f, 0.f, 0.f };
    f32x4 acc[2][2];

    // ---- d2 = relu(GN(d1 @ Wd2^T)) -> bfD ----
    acc[0][0] = z; acc[0][1] = z; acc[1][0] = z; acc[1][1] = z;
    gemm_k128(bfD, Wd2, lane, wave, acc);
    gn_store(acc, g_d2, bt_d2, stg, red_s, red_q, bfD, t);

    // ---- q = relu(GN(agts[hi] @ Wq^T)) -> bfQ ----
    acc[0][0] = z; acc[0][1] = z; acc[1][0] = z; acc[1][1] = z;
    gemm_k128(bfA, Wq, lane, wave, acc);
    gn_store(acc, g_q, bt_q, stg, red_s, red_q, bfQ, t);

    // ---- c1 = relu(GN([d2|q|ctx] @ Wc1^T)) -> bfA ----  (K = 384)
    acc[0][0] = z; acc[0][1] = z; acc[1][0] = z; acc[1][1] = z;
#pragma unroll
    for (int kt = 0; kt < 12; ++kt) {
        const unsigned short* Ab = (kt < 4) ? bfD : (kt < 8) ? bfQ : bfX;
        const int k = kt & 3;
        const int koff = k * 32 + (lane >> 4) * 8;
        bf16x8 a[2], b[2];
#pragma unroll
        for (int m = 0; m < 2; ++m) {
            int r = m * 16 + (lane & 15);
            int byte = (r * 256 + koff * 2) ^ ((r & 7) << 4);
            a[m] = *(const bf16x8*)((const char*)Ab + byte);
        }
#pragma unroll
        for (int n = 0; n < 2; ++n) {
            int wr = wave * 32 + n * 16 + (lane & 15);
            b[n] = *(const bf16x8*)(Wc1 + (size_t)wr * 384 + kt * 32 + (lane >> 4) * 8);
        }
#pragma unroll
        for (int m = 0; m < 2; ++m)
#pragma unroll
            for (int n = 0; n < 2; ++n)
                acc[m][n] = __builtin_amdgcn_mfma_f32_16x16x32_bf16(a[m], b[n], acc[m][n], 0, 0, 0);
    }
    gn_store(acc, g_c1, bt_c1, stg, red_s, red_q, bfA, t);

    // ---- e = c1 @ Wc2^T ; scatter-add to outbuf[hi] ----
    acc[0][0] = z; acc[0][1] = z; acc[1][0] = z; acc[1][1] = z;
    gemm_k128(bfA, Wc2, lane, wave, acc);
#pragma unroll
    for (int m = 0; m < 2; ++m)
#pragma unroll
        for (int n = 0; n < 2; ++n)
#pragma unroll
            for (int j = 0; j < 4; ++j) {
                int r = m * 16 + ((lane >> 4) << 2) + j;
                if (e0 + r < E)
                    atomicAdd(&outbuf[(size_t)sh_h[r] * NCH + wave * 32 + n * 16 + (lane & 15)],
                              acc[m][n][j]);
            }
}

// ---------------------------------------------------------------------------
// out = agts @ w_a^T   (per node 128x128 matvec), batched TB nodes per block
// ---------------------------------------------------------------------------
__global__ __launch_bounds__(128) void node_init_kernel(
    const float* __restrict__ agts, const float* __restrict__ w_a,
    float* __restrict__ outbuf, int N)
{
    const int t  = threadIdx.x;
    const int n0 = blockIdx.x * TB;
    __shared__ float sh[TB][NCH];
#pragma unroll
    for (int i = 0; i < TB; ++i) {
        int n = n0 + i; if (n >= N) n = N - 1;
        sh[i][t] = agts[(size_t)n * NCH + t];
    }
    __syncthreads();
    float acc[TB];
#pragma unroll
    for (int i = 0; i < TB; ++i) acc[i] = 0.f;
    const float4* wr = (const float4*)(w_a + (size_t)t * NCH);
    for (int k4 = 0; k4 < NCH / 4; ++k4) {
        float4 wv = wr[k4];
#pragma unroll
        for (int i = 0; i < TB; ++i) {
            float4 xv = *(const float4*)&sh[i][k4 * 4];
            acc[i] = fmaf(wv.x, xv.x, acc[i]);
            acc[i] = fmaf(wv.y, xv.y, acc[i]);
            acc[i] = fmaf(wv.z, xv.z, acc[i]);
            acc[i] = fmaf(wv.w, xv.w, acc[i]);
        }
    }
#pragma unroll
    for (int i = 0; i < TB; ++i) {
        int n = n0 + i;
        if (n < N) outbuf[(size_t)n * NCH + t] = acc[i];
    }
}

// ---------------------------------------------------------------------------
// Node post: relu(GN(out)) -> GN(out @ w_l^T) -> relu(+ res), in place (f32)
// ---------------------------------------------------------------------------
__global__ __launch_bounds__(128) void node_post_kernel(
    float* __restrict__ outbuf, const float* __restrict__ agts,
    const float* __restrict__ g_n, const float* __restrict__ bt_n,
    const float* __restrict__ w_l, const float* __restrict__ g_l, const float* __restrict__ bt_l,
    int N)
{
    const int t  = threadIdx.x;
    const int n0 = blockIdx.x * TB;
    __shared__ float sh[TB][NCH];
    __shared__ float red_s[TB][2], red_q2[TB][2];

    float acc[TB];
#pragma unroll
    for (int i = 0; i < TB; ++i) {
        int n = n0 + i; if (n >= N) n = N - 1;
        acc[i] = outbuf[(size_t)n * NCH + t];
    }
    // GN(g_n) + relu -> sh
    __syncthreads();
#pragma unroll
    for (int i = 0; i < TB; ++i) {
        float s = acc[i];
        float q = acc[i] * acc[i];
        for (int off = 32; off > 0; off >>= 1) {
            s += __shfl_down(s, off);
            q += __shfl_down(q, off);
        }
        if ((t & 63) == 0) { red_s[i][t >> 6] = s; red_q2[i][t >> 6] = q; }
    }
    __syncthreads();
    {
        const float g = g_n[t], b = bt_n[t];
#pragma unroll
        for (int i = 0; i < TB; ++i) {
            float s  = red_s[i][0] + red_s[i][1];
            float q  = red_q2[i][0] + red_q2[i][1];
            float mu = s * (1.f / NCH);
            float var = q * (1.f / NCH) - mu * mu;
            float rs = rsqrtf(var + 1e-5f);
            sh[i][t] = fmaxf((acc[i] - mu) * rs * g + b, 0.f);
        }
    }
    __syncthreads();

    // linear: acc = W_l @ sh
#pragma unroll
    for (int i = 0; i < TB; ++i) acc[i] = 0.f;
    const float4* wr = (const float4*)(w_l + (size_t)t * NCH);
    for (int k4 = 0; k4 < NCH / 4; ++k4) {
        float4 wv = wr[k4];
#pragma unroll
        for (int i = 0; i < TB; ++i) {
            float4 xv = *(const float4*)&sh[i][k4 * 4];
            acc[i] = fmaf(wv.x, xv.x, acc[i]);
            acc[i] = fmaf(wv.y, xv.y, acc[i]);
            acc[i] = fmaf(wv.z, xv.z, acc[i]);
            acc[i] = fmaf(wv.w, xv.w, acc[i]);
        }
    }
    // GN(g_l) (no relu), + residual, relu, store in place
    __syncthreads();
#pragma unroll
    for (int i = 0; i < TB; ++i) {
        float s = acc[i];
        float q = acc[i] * acc[i];
        for (int off = 32; off > 0; off >>= 1) {
            s += __shfl_down(s, off);
            q += __shfl_down(q, off);
        }
        if ((t & 63) == 0) { red_s[i][t >> 6] = s; red_q2[i][t >> 6] = q; }
    }
    __syncthreads();
    const float g = g_l[t];
    const float b = bt_l[t];
#pragma unroll
    for (int i = 0; i < TB; ++i) {
        float s  = red_s[i][0] + red_s[i][1];
        float q  = red_q2[i][0] + red_q2[i][1];
        float mu = s * (1.f / NCH);
        float var = q * (1.f / NCH) - mu * mu;
        float rs = rsqrtf(var + 1e-5f);
        float v  = (acc[i] - mu) * rs * g + b;
        int n = n0 + i;
        if (n < N) {
            float r = agts[(size_t)n * NCH + t];
            outbuf[(size_t)n * NCH + t] = fmaxf(v + r, 0.f);
        }
    }
}

// ---------------------------------------------------------------------------
extern "C" void kernel_launch(void* const* d_in, const int* in_sizes, int n_in,
                              void* d_out, int out_size, void* d_ws, size_t ws_size,
                              hipStream_t stream) {
    const float* agts     = (const float*)d_in[0];
    const float* ctx      = (const float*)d_in[1];
    const float* agt_ctrs = (const float*)d_in[2];
    const float* ctx_ctrs = (const float*)d_in[3];
    const int*   hi       = (const int*)d_in[4];
    const int*   wi       = (const int*)d_in[5];
    const float* w_d1     = (const float*)d_in[6];
    const float* b_d1     = (const float*)d_in[7];
    const float* w_d2     = (const float*)d_in[8];
    const float* g_d2     = (const float*)d_in[9];
    const float* bt_d2    = (const float*)d_in[10];
    const float* w_q      = (const float*)d_in[11];
    const float* g_q      = (const float*)d_in[12];
    const float* bt_q     = (const float*)d_in[13];
    const float* w_c1     = (const float*)d_in[14];
    const float* g_c1     = (const float*)d_in[15];
    const float* bt_c1    = (const float*)d_in[16];
    const float* w_c2     = (const float*)d_in[17];
    const float* w_a      = (const float*)d_in[18];
    const float* g_n      = (const float*)d_in[19];
    const float* bt_n     = (const float*)d_in[20];
    const float* w_l      = (const float*)d_in[21];
    const float* g_l      = (const float*)d_in[22];
    const float* bt_l     = (const float*)d_in[23];

    const int N = in_sizes[0] / NCH;
    const int E = in_sizes[4];

    float* outbuf = (float*)d_out;                 // [N,128] f32 accumulator
    unsigned short* wbf = (unsigned short*)d_ws;   // bf16 weights (196 KB)

    const int nb_nodes = (N + TB - 1) / TB;
    const int nb_edges = (E + EB - 1) / EB;

    convert_weights_kernel<<<384, 256, 0, stream>>>(w_d2, w_q, w_c1, w_c2, wbf);
    node_init_kernel<<<nb_nodes, 128, 0, stream>>>(agts, w_a, outbuf, N);
    edge_kernel<<<nb_edges, 256, 0, stream>>>(
        agts, ctx, agt_ctrs, ctx_ctrs, hi, wi,
        w_d1, b_d1, g_d2, bt_d2, g_q, bt_q, g_c1, bt_c1,
        wbf, outbuf, E);
    node_post_kernel<<<nb_nodes, 128, 0, stream>>>(
        outbuf, agts, g_n, bt_n, w_l, g_l, bt_l, N);
}

// Round 4
// 400.910 us; speedup vs baseline: 4.7331x; 1.4435x over previous
//
#include <hip/hip_runtime.h>
#include <hip/hip_bf16.h>

#define NCH 128      // n_agt == n_ctx
#define EB  32       // edges per block (edge kernel)
#define TB  16       // nodes per block (node kernels)

typedef __attribute__((ext_vector_type(8))) short bf16x8;
typedef __attribute__((ext_vector_type(4))) float f32x4;

__device__ inline unsigned short f2bf(float v) {
    __hip_bfloat16 h = __float2bfloat16(v);
    return __builtin_bit_cast(unsigned short, h);
}

// ---------------------------------------------------------------------------
// Convert the four edge-GEMM weight matrices to bf16 in d_ws.
// Layout: Wd2[128x128] | Wq[128x128] | Wc1[128x384] | Wc2[128x128]
// ---------------------------------------------------------------------------
__global__ __launch_bounds__(256) void convert_weights_kernel(
    const float* __restrict__ w_d2, const float* __restrict__ w_q,
    const float* __restrict__ w_c1, const float* __restrict__ w_c2,
    unsigned short* __restrict__ out)
{
    int i = blockIdx.x * 256 + threadIdx.x;
    const float* src; int off;
    if      (i < 16384) { src = w_d2; off = i; }
    else if (i < 32768) { src = w_q;  off = i - 16384; }
    else if (i < 81920) { src = w_c1; off = i - 32768; }
    else if (i < 98304) { src = w_c2; off = i - 81920; }
    else return;
    out[i] = f2bf(src[off]);
}

// ---------------------------------------------------------------------------
// One K=128 GEMM step on 32 edges: acc[m][n] += A(32x128,bf16,swizzled LDS)
//   x W^T (W row-major [128 out][128 k] bf16, from global/L2).
// Wave covers out-channels [wave*32, wave*32+32), all 32 edge rows.
// ---------------------------------------------------------------------------
__device__ inline void gemm_k128(const unsigned short* A, const unsigned short* W,
                                 int lane, int wave, f32x4 (&acc)[2][2])
{
#pragma unroll
    for (int k = 0; k < 4; ++k) {
        const int koff = k * 32 + (lane >> 4) * 8;
        bf16x8 a[2], b[2];
#pragma unroll
        for (int m = 0; m < 2; ++m) {
            int r = m * 16 + (lane & 15);
            int byte = (r * 256 + koff * 2) ^ ((r & 7) << 4);
            a[m] = *(const bf16x8*)((const char*)A + byte);
        }
#pragma unroll
        for (int n = 0; n < 2; ++n) {
            int wr = wave * 32 + n * 16 + (lane & 15);
            b[n] = *(const bf16x8*)(W + (size_t)wr * NCH + koff);
        }
#pragma unroll
        for (int m = 0; m < 2; ++m)
#pragma unroll
            for (int n = 0; n < 2; ++n)
                acc[m][n] = __builtin_amdgcn_mfma_f32_16x16x32_bf16(a[m], b[n], acc[m][n], 0, 0, 0);
    }
}

// ---------------------------------------------------------------------------
// Fragment-domain GroupNorm(1) + ReLU + bf16 pack + swizzled LDS store.
// C-frag layout (16x16x32): row = m*16 + (lane>>4)*4 + j, col = wave*32 + n*16 + (lane&15).
// Row-sum = shfl_xor reduce over lane&15 (4 levels) + cross-wave via [32][4] LDS.
// ---------------------------------------------------------------------------
__device__ inline void gn_frag_store(f32x4 (&acc)[2][2],
                                     const float* __restrict__ gamma,
                                     const float* __restrict__ beta,
                                     float (*red_s)[4], float (*red_q)[4],
                                     unsigned short* dst, int t)
{
    const int lane = t & 63, wave = t >> 6;
    float s[2][4], q[2][4];
#pragma unroll
    for (int m = 0; m < 2; ++m)
#pragma unroll
        for (int j = 0; j < 4; ++j) {
            float sv = acc[m][0][j] + acc[m][1][j];
            float qv = acc[m][0][j] * acc[m][0][j] + acc[m][1][j] * acc[m][1][j];
#pragma unroll
            for (int off = 1; off < 16; off <<= 1) {
                sv += __shfl_xor(sv, off);
                qv += __shfl_xor(qv, off);
            }
            s[m][j] = sv; q[m][j] = qv;
        }
    if ((lane & 15) == 0) {
        const int rg = lane >> 4;
#pragma unroll
        for (int m = 0; m < 2; ++m)
#pragma unroll
            for (int j = 0; j < 4; ++j) {
                int r = m * 16 + rg * 4 + j;
                red_s[r][wave] = s[m][j];
                red_q[r][wave] = q[m][j];
            }
    }
    __syncthreads();   // also: all waves done reading dst (A of previous GEMM)

    const int c0 = wave * 32 + (lane & 15);
    const float g0 = gamma[c0],      b0 = beta[c0];
    const float g1 = gamma[c0 + 16], b1 = beta[c0 + 16];
#pragma unroll
    for (int m = 0; m < 2; ++m)
#pragma unroll
        for (int j = 0; j < 4; ++j) {
            int r = m * 16 + ((lane >> 4) << 2) + j;
            float4 sv = *(const float4*)red_s[r];
            float4 qv = *(const float4*)red_q[r];
            float ssum = (sv.x + sv.y) + (sv.z + sv.w);
            float qsum = (qv.x + qv.y) + (qv.z + qv.w);
            float mu  = ssum * (1.f / NCH);
            float var = qsum * (1.f / NCH) - mu * mu;
            float rs  = rsqrtf(var + 1e-5f);
            float v0 = fmaxf((acc[m][0][j] - mu) * rs * g0 + b0, 0.f);
            float v1 = fmaxf((acc[m][1][j] - mu) * rs * g1 + b1, 0.f);
            unsigned int p0 = f2bf(v0), p1 = f2bf(v1);
            unsigned int o0 = __shfl_xor((int)p0, 1), o1 = __shfl_xor((int)p1, 1);
            if (!(lane & 1)) {
                int cb = c0 * 2;  // even byte-col
                int byte0 = (r * 256 + cb) ^ ((r & 7) << 4);
                int byte1 = (r * 256 + cb + 32) ^ ((r & 7) << 4);
                *(unsigned int*)((char*)dst + byte0) = (p0 & 0xffffu) | (o0 << 16);
                *(unsigned int*)((char*)dst + byte1) = (p1 & 0xffffu) | (o1 << 16);
            }
        }
    __syncthreads();
}

// ---------------------------------------------------------------------------
// Fused edge pipeline (MFMA): d1 -> d2(GN) ; q(GN) ; c1(GN, K=384) ; c2 -> scatter
// ---------------------------------------------------------------------------
__global__ __launch_bounds__(256) void edge_kernel(
    const float* __restrict__ agts, const float* __restrict__ ctx,
    const float* __restrict__ agt_ctrs, const float* __restrict__ ctx_ctrs,
    const int* __restrict__ hi, const int* __restrict__ wi,
    const float* __restrict__ w_d1, const float* __restrict__ b_d1,
    const float* __restrict__ g_d2, const float* __restrict__ bt_d2,
    const float* __restrict__ g_q, const float* __restrict__ bt_q,
    const float* __restrict__ g_c1, const float* __restrict__ bt_c1,
    const unsigned short* __restrict__ wbf,
    float* __restrict__ outbuf, int E)
{
    const int t = threadIdx.x;
    const int lane = t & 63;
    const int wave = t >> 6;
    const int e0 = blockIdx.x * EB;

    __shared__ unsigned short bfA[EB * NCH];   // agts[hi] bf16; later c1
    __shared__ unsigned short bfD[EB * NCH];   // d1; later d2
    __shared__ unsigned short bfQ[EB * NCH];   // q
    __shared__ unsigned short bfX[EB * NCH];   // ctx[wi]
    __shared__ __align__(16) float red_s[EB][4];
    __shared__ __align__(16) float red_q[EB][4];
    __shared__ int   sh_h[EB], sh_w[EB];
    __shared__ float sh_dx[EB], sh_dy[EB];

    const unsigned short* Wd2 = wbf;
    const unsigned short* Wq  = wbf + 16384;
    const unsigned short* Wc1 = wbf + 32768;
    const unsigned short* Wc2 = wbf + 81920;

    if (t < EB) {
        int e = e0 + t; if (e >= E) e = E - 1;
        int h = hi[e], w = wi[e];
        sh_h[t] = h; sh_w[t] = w;
        sh_dx[t] = agt_ctrs[2 * h]     - ctx_ctrs[2 * w];
        sh_dy[t] = agt_ctrs[2 * h + 1] - ctx_ctrs[2 * w + 1];
    }
    __syncthreads();

    // gather agts[hi], ctx[wi] -> bf16 swizzled LDS (float4 loads, 8B LDS stores)
    {
        const int c4 = (t & 31) * 4;
        const int rr = t >> 5;
#pragma unroll
        for (int p = 0; p < 4; ++p) {
            int r = p * 8 + rr;
            float4 av = *(const float4*)&agts[(size_t)sh_h[r] * NCH + c4];
            float4 xv = *(const float4*)&ctx [(size_t)sh_w[r] * NCH + c4];
            int byte = (r * 256 + c4 * 2) ^ ((r & 7) << 4);
            ushort4 ao = { f2bf(av.x), f2bf(av.y), f2bf(av.z), f2bf(av.w) };
            ushort4 xo = { f2bf(xv.x), f2bf(xv.y), f2bf(xv.z), f2bf(xv.w) };
            *(ushort4*)((char*)bfA + byte) = ao;
            *(ushort4*)((char*)bfX + byte) = xo;
        }
    }
    // d1 = relu(w_d1 . [dx,dy] + b_d1)   -> bfD
    {
        const int c = t & 127, rh = t >> 7;
        const float w0 = w_d1[2 * c], w1 = w_d1[2 * c + 1], b0 = b_d1[c];
#pragma unroll
        for (int i = 0; i < 16; ++i) {
            int r = rh * 16 + i;
            float v = fmaxf(fmaf(w0, sh_dx[r], fmaf(w1, sh_dy[r], b0)), 0.f);
            unsigned int pv = f2bf(v);
            unsigned int ov = __shfl_xor((int)pv, 1);
            if (!(c & 1)) {
                int byte = (r * 256 + c * 2) ^ ((r & 7) << 4);
                *(unsigned int*)((char*)bfD + byte) = (pv & 0xffffu) | (ov << 16);
            }
        }
    }
    __syncthreads();

    const f32x4 z = { 0.f, 0.f, 0.f, 0.f };
    f32x4 acc[2][2];

    // ---- d2 = relu(GN(d1 @ Wd2^T)) -> bfD ----
    acc[0][0] = z; acc[0][1] = z; acc[1][0] = z; acc[1][1] = z;
    gemm_k128(bfD, Wd2, lane, wave, acc);
    gn_frag_store(acc, g_d2, bt_d2, red_s, red_q, bfD, t);

    // ---- q = relu(GN(agts[hi] @ Wq^T)) -> bfQ ----
    acc[0][0] = z; acc[0][1] = z; acc[1][0] = z; acc[1][1] = z;
    gemm_k128(bfA, Wq, lane, wave, acc);
    gn_frag_store(acc, g_q, bt_q, red_s, red_q, bfQ, t);

    // ---- c1 = relu(GN([d2|q|ctx] @ Wc1^T)) -> bfA ----  (K = 384)
    acc[0][0] = z; acc[0][1] = z; acc[1][0] = z; acc[1][1] = z;
#pragma unroll
    for (int kt = 0; kt < 12; ++kt) {
        const unsigned short* Ab = (kt < 4) ? bfD : (kt < 8) ? bfQ : bfX;
        const int k = kt & 3;
        const int koff = k * 32 + (lane >> 4) * 8;
        bf16x8 a[2], b[2];
#pragma unroll
        for (int m = 0; m < 2; ++m) {
            int r = m * 16 + (lane & 15);
            int byte = (r * 256 + koff * 2) ^ ((r & 7) << 4);
            a[m] = *(const bf16x8*)((const char*)Ab + byte);
        }
#pragma unroll
        for (int n = 0; n < 2; ++n) {
            int wr = wave * 32 + n * 16 + (lane & 15);
            b[n] = *(const bf16x8*)(Wc1 + (size_t)wr * 384 + kt * 32 + (lane >> 4) * 8);
        }
#pragma unroll
        for (int m = 0; m < 2; ++m)
#pragma unroll
            for (int n = 0; n < 2; ++n)
                acc[m][n] = __builtin_amdgcn_mfma_f32_16x16x32_bf16(a[m], b[n], acc[m][n], 0, 0, 0);
    }
    gn_frag_store(acc, g_c1, bt_c1, red_s, red_q, bfA, t);

    // ---- e = c1 @ Wc2^T ; scatter-add to outbuf[hi] ----
    acc[0][0] = z; acc[0][1] = z; acc[1][0] = z; acc[1][1] = z;
    gemm_k128(bfA, Wc2, lane, wave, acc);
#pragma unroll
    for (int m = 0; m < 2; ++m)
#pragma unroll
        for (int n = 0; n < 2; ++n)
#pragma unroll
            for (int j = 0; j < 4; ++j) {
                int r = m * 16 + ((lane >> 4) << 2) + j;
                if (e0 + r < E)
                    atomicAdd(&outbuf[(size_t)sh_h[r] * NCH + wave * 32 + n * 16 + (lane & 15)],
                              acc[m][n][j]);
            }
}

// ---------------------------------------------------------------------------
// out = agts @ w_a^T   (per node 128x128 matvec), batched TB nodes per block
// ---------------------------------------------------------------------------
__global__ __launch_bounds__(128) void node_init_kernel(
    const float* __restrict__ agts, const float* __restrict__ w_a,
    float* __restrict__ outbuf, int N)
{
    const int t  = threadIdx.x;
    const int n0 = blockIdx.x * TB;
    __shared__ float sh[TB][NCH];
#pragma unroll
    for (int i = 0; i < TB; ++i) {
        int n = n0 + i; if (n >= N) n = N - 1;
        sh[i][t] = agts[(size_t)n * NCH + t];
    }
    __syncthreads();
    float acc[TB];
#pragma unroll
    for (int i = 0; i < TB; ++i) acc[i] = 0.f;
    const float4* wr = (const float4*)(w_a + (size_t)t * NCH);
    for (int k4 = 0; k4 < NCH / 4; ++k4) {
        float4 wv = wr[k4];
#pragma unroll
        for (int i = 0; i < TB; ++i) {
            float4 xv = *(const float4*)&sh[i][k4 * 4];
            acc[i] = fmaf(wv.x, xv.x, acc[i]);
            acc[i] = fmaf(wv.y, xv.y, acc[i]);
            acc[i] = fmaf(wv.z, xv.z, acc[i]);
            acc[i] = fmaf(wv.w, xv.w, acc[i]);
        }
    }
#pragma unroll
    for (int i = 0; i < TB; ++i) {
        int n = n0 + i;
        if (n < N) outbuf[(size_t)n * NCH + t] = acc[i];
    }
}

// ---------------------------------------------------------------------------
// Node post: relu(GN(out)) -> GN(out @ w_l^T) -> relu(+ res), in place (f32)
// ---------------------------------------------------------------------------
__global__ __launch_bounds__(128) void node_post_kernel(
    float* __restrict__ outbuf, const float* __restrict__ agts,
    const float* __restrict__ g_n, const float* __restrict__ bt_n,
    const float* __restrict__ w_l, const float* __restrict__ g_l, const float* __restrict__ bt_l,
    int N)
{
    const int t  = threadIdx.x;
    const int n0 = blockIdx.x * TB;
    __shared__ float sh[TB][NCH];
    __shared__ float red_s[TB][2], red_q2[TB][2];

    float acc[TB];
#pragma unroll
    for (int i = 0; i < TB; ++i) {
        int n = n0 + i; if (n >= N) n = N - 1;
        acc[i] = outbuf[(size_t)n * NCH + t];
    }
    // GN(g_n) + relu -> sh
    __syncthreads();
#pragma unroll
    for (int i = 0; i < TB; ++i) {
        float s = acc[i];
        float q = acc[i] * acc[i];
        for (int off = 32; off > 0; off >>= 1) {
            s += __shfl_down(s, off);
            q += __shfl_down(q, off);
        }
        if ((t & 63) == 0) { red_s[i][t >> 6] = s; red_q2[i][t >> 6] = q; }
    }
    __syncthreads();
    {
        const float g = g_n[t], b = bt_n[t];
#pragma unroll
        for (int i = 0; i < TB; ++i) {
            float s  = red_s[i][0] + red_s[i][1];
            float q  = red_q2[i][0] + red_q2[i][1];
            float mu = s * (1.f / NCH);
            float var = q * (1.f / NCH) - mu * mu;
            float rs = rsqrtf(var + 1e-5f);
            sh[i][t] = fmaxf((acc[i] - mu) * rs * g + b, 0.f);
        }
    }
    __syncthreads();

    // linear: acc = W_l @ sh
#pragma unroll
    for (int i = 0; i < TB; ++i) acc[i] = 0.f;
    const float4* wr = (const float4*)(w_l + (size_t)t * NCH);
    for (int k4 = 0; k4 < NCH / 4; ++k4) {
        float4 wv = wr[k4];
#pragma unroll
        for (int i = 0; i < TB; ++i) {
            float4 xv = *(const float4*)&sh[i][k4 * 4];
            acc[i] = fmaf(wv.x, xv.x, acc[i]);
            acc[i] = fmaf(wv.y, xv.y, acc[i]);
            acc[i] = fmaf(wv.z, xv.z, acc[i]);
            acc[i] = fmaf(wv.w, xv.w, acc[i]);
        }
    }
    // GN(g_l) (no relu), + residual, relu, store in place
    __syncthreads();
#pragma unroll
    for (int i = 0; i < TB; ++i) {
        float s = acc[i];
        float q = acc[i] * acc[i];
        for (int off = 32; off > 0; off >>= 1) {
            s += __shfl_down(s, off);
            q += __shfl_down(q, off);
        }
        if ((t & 63) == 0) { red_s[i][t >> 6] = s; red_q2[i][t >> 6] = q; }
    }
    __syncthreads();
    const float g = g_l[t];
    const float b = bt_l[t];
#pragma unroll
    for (int i = 0; i < TB; ++i) {
        float s  = red_s[i][0] + red_s[i][1];
        float q  = red_q2[i][0] + red_q2[i][1];
        float mu = s * (1.f / NCH);
        float var = q * (1.f / NCH) - mu * mu;
        float rs = rsqrtf(var + 1e-5f);
        float v  = (acc[i] - mu) * rs * g + b;
        int n = n0 + i;
        if (n < N) {
            float r = agts[(size_t)n * NCH + t];
            outbuf[(size_t)n * NCH + t] = fmaxf(v + r, 0.f);
        }
    }
}

// ---------------------------------------------------------------------------
extern "C" void kernel_launch(void* const* d_in, const int* in_sizes, int n_in,
                              void* d_out, int out_size, void* d_ws, size_t ws_size,
                              hipStream_t stream) {
    const float* agts     = (const float*)d_in[0];
    const float* ctx      = (const float*)d_in[1];
    const float* agt_ctrs = (const float*)d_in[2];
    const float* ctx_ctrs = (const float*)d_in[3];
    const int*   hi       = (const int*)d_in[4];
    const int*   wi       = (const int*)d_in[5];
    const float* w_d1     = (const float*)d_in[6];
    const float* b_d1     = (const float*)d_in[7];
    const float* w_d2     = (const float*)d_in[8];
    const float* g_d2     = (const float*)d_in[9];
    const float* bt_d2    = (const float*)d_in[10];
    const float* w_q      = (const float*)d_in[11];
    const float* g_q      = (const float*)d_in[12];
    const float* bt_q     = (const float*)d_in[13];
    const float* w_c1     = (const float*)d_in[14];
    const float* g_c1     = (const float*)d_in[15];
    const float* bt_c1    = (const float*)d_in[16];
    const float* w_c2     = (const float*)d_in[17];
    const float* w_a      = (const float*)d_in[18];
    const float* g_n      = (const float*)d_in[19];
    const float* bt_n     = (const float*)d_in[20];
    const float* w_l      = (const float*)d_in[21];
    const float* g_l      = (const float*)d_in[22];
    const float* bt_l     = (const float*)d_in[23];

    const int N = in_sizes[0] / NCH;
    const int E = in_sizes[4];

    float* outbuf = (float*)d_out;                 // [N,128] f32 accumulator
    unsigned short* wbf = (unsigned short*)d_ws;   // bf16 weights (196 KB)

    const int nb_nodes = (N + TB - 1) / TB;
    const int nb_edges = (E + EB - 1) / EB;

    convert_weights_kernel<<<384, 256, 0, stream>>>(w_d2, w_q, w_c1, w_c2, wbf);
    node_init_kernel<<<nb_nodes, 128, 0, stream>>>(agts, w_a, outbuf, N);
    edge_kernel<<<nb_edges, 256, 0, stream>>>(
        agts, ctx, agt_ctrs, ctx_ctrs, hi, wi,
        w_d1, b_d1, g_d2, bt_d2, g_q, bt_q, g_c1, bt_c1,
        wbf, outbuf, E);
    node_post_kernel<<<nb_nodes, 128, 0, stream>>>(
        outbuf, agts, g_n, bt_n, w_l, g_l, bt_l, N);
}